// Round 1
// baseline (561.719 us; speedup 1.0000x reference)
//
#include <hip/hip_runtime.h>
#include <math.h>

constexpr int F = 128;        // in features
constexpr int H = 64;         // out features
constexpr int NB = 32;        // nodes per gemm block
constexpr int XS_STRIDE = F + 4;  // pad to avoid 4-way LDS bank conflict

// ---------------- init: deg = 1 (self loop), zero scalar accumulator --------
__global__ __launch_bounds__(256) void k_init(float* __restrict__ deg,
                                              float* __restrict__ acc, int N) {
  int i = blockIdx.x * 256 + threadIdx.x;
  if (i < N) deg[i] = 1.0f;
  if (i == 0) acc[0] = 0.0f;
}

// ---------------- deg[dst] += w ---------------------------------------------
__global__ __launch_bounds__(256) void k_deg(const int* __restrict__ dst,
                                             const float* __restrict__ w,
                                             float* __restrict__ deg, int E) {
  int e = blockIdx.x * 256 + threadIdx.x;
  if (e < E) atomicAdd(&deg[dst[e]], w[e]);
}

// ---------------- dinv = rsqrt(deg) in place --------------------------------
__global__ __launch_bounds__(256) void k_dinv(float* __restrict__ deg, int N) {
  int i = blockIdx.x * 256 + threadIdx.x;
  if (i < N) {
    float d = deg[i];
    deg[i] = d > 0.0f ? rsqrtf(d) : 0.0f;
  }
}

// ---------------- h = x @ W  (N x 128) @ (128 x 64) -------------------------
__global__ __launch_bounds__(256) void k_gemm(const float* __restrict__ x,
                                              const float* __restrict__ W,
                                              float* __restrict__ h, int N) {
  __shared__ float Ws[F * H];            // 32 KB, [k][f]
  __shared__ float xs[NB * XS_STRIDE];   // ~16.5 KB, [nl][k] padded
  const int t = threadIdx.x;
  {
    const float4* W4 = (const float4*)W;
    float4* Ws4 = (float4*)Ws;
#pragma unroll
    for (int i = 0; i < (F * H / 4) / 256; ++i) Ws4[t + i * 256] = W4[t + i * 256];
  }
  const int node0 = blockIdx.x * NB;
  {
    const float4* x4 = (const float4*)(x + (size_t)node0 * F);
    int lim = (N - node0 < NB ? N - node0 : NB) * (F / 4);
    for (int i = t; i < NB * (F / 4); i += 256) {
      int nl = i / (F / 4), kk = i % (F / 4);
      float4 v = (i < lim) ? x4[i] : make_float4(0.f, 0.f, 0.f, 0.f);
      *(float4*)&xs[nl * XS_STRIDE + kk * 4] = v;
    }
  }
  __syncthreads();
  const int f0 = (t & 15) * 4;
  const int nl0 = (t >> 4) * 2;
  float acc[2][4] = {};
  for (int k = 0; k < F; k += 4) {
    float xr[2][4];
    float wr[4][4];
    *(float4*)&xr[0][0] = *(const float4*)&xs[(nl0 + 0) * XS_STRIDE + k];
    *(float4*)&xr[1][0] = *(const float4*)&xs[(nl0 + 1) * XS_STRIDE + k];
#pragma unroll
    for (int i = 0; i < 4; ++i)
      *(float4*)&wr[i][0] = *(const float4*)&Ws[(k + i) * H + f0];
#pragma unroll
    for (int i = 0; i < 4; ++i)
#pragma unroll
      for (int n = 0; n < 2; ++n)
#pragma unroll
        for (int j = 0; j < 4; ++j)
          acc[n][j] += xr[n][i] * wr[i][j];
  }
#pragma unroll
  for (int n = 0; n < 2; ++n) {
    int node = node0 + nl0 + n;
    if (node < N)
      *(float4*)&h[(size_t)node * H + f0] =
          make_float4(acc[n][0], acc[n][1], acc[n][2], acc[n][3]);
  }
}

// ---------------- out[n][f] = b[f] + dinv[n]^2 * h[n][f] (self loop) --------
__global__ __launch_bounds__(256) void k_outinit(const float* __restrict__ h,
                                                 const float* __restrict__ dinv,
                                                 const float* __restrict__ b,
                                                 float* __restrict__ out, int N) {
  int i = blockIdx.x * 256 + threadIdx.x;
  if (i < N * H) {
    int n = i >> 6, f = i & 63;
    float di = dinv[n];
    out[i] = b[f] + di * di * h[i];
  }
}

// ---------------- edge scatter: out[dst] += dinv[s]*w*dinv[d] * h[src] ------
__global__ __launch_bounds__(256) void k_scatter(const int* __restrict__ src,
                                                 const int* __restrict__ dst,
                                                 const float* __restrict__ w,
                                                 const float* __restrict__ dinv,
                                                 const float* __restrict__ h,
                                                 float* __restrict__ out, int E) {
  int e = blockIdx.x * 4 + (threadIdx.x >> 6);
  if (e >= E) return;
  int lane = threadIdx.x & 63;
  int s = src[e], d = dst[e];
  float nrm = dinv[s] * w[e] * dinv[d];
  float val = nrm * h[(size_t)s * H + lane];
  atomicAdd(&out[(size_t)d * H + lane], val);
}

// ---------------- fused relu + dot with fc_w, block partial -> atomic -------
__global__ __launch_bounds__(256) void k_reduce(const float* __restrict__ oacc,
                                                const float* __restrict__ fcw,
                                                float* __restrict__ acc, int total) {
  float s = 0.f;
  int idx = blockIdx.x * 256 + threadIdx.x;
  int stride = gridDim.x * 256;
  const float4* a4 = (const float4*)oacc;
  const float4* w4 = (const float4*)fcw;
  int n4 = total / 4;
  for (int i = idx; i < n4; i += stride) {
    float4 a = a4[i], w = w4[i];
    s += fmaxf(a.x, 0.f) * w.x + fmaxf(a.y, 0.f) * w.y +
         fmaxf(a.z, 0.f) * w.z + fmaxf(a.w, 0.f) * w.w;
  }
#pragma unroll
  for (int off = 32; off > 0; off >>= 1) s += __shfl_down(s, off);
  __shared__ float ls[4];
  if ((threadIdx.x & 63) == 0) ls[threadIdx.x >> 6] = s;
  __syncthreads();
  if (threadIdx.x == 0) atomicAdd(acc, ls[0] + ls[1] + ls[2] + ls[3]);
}

// ---------------- sigmoid epilogue ------------------------------------------
__global__ void k_final(const float* __restrict__ acc,
                        const float* __restrict__ fcb,
                        float* __restrict__ out) {
  if (threadIdx.x == 0) {
    float logit = acc[0] + fcb[0];
    out[0] = 1.0f / (1.0f + expf(-logit));
  }
}

extern "C" void kernel_launch(void* const* d_in, const int* in_sizes, int n_in,
                              void* d_out, int out_size, void* d_ws, size_t ws_size,
                              hipStream_t stream) {
  const float* x      = (const float*)d_in[0];
  const int*   elist  = (const int*)d_in[1];
  const float* eattr  = (const float*)d_in[2];
  const float* conv_w = (const float*)d_in[3];
  const float* conv_b = (const float*)d_in[4];
  const float* fc_w   = (const float*)d_in[5];
  const float* fc_b   = (const float*)d_in[6];
  float* out = (float*)d_out;

  const int N = in_sizes[0] / F;   // 50000
  const int E = in_sizes[2];       // 1,600,000
  const int* src = elist;
  const int* dst = elist + E;

  float* ws   = (float*)d_ws;
  float* deg  = ws;                      // N floats (becomes dinv in place)
  float* h    = ws + N;                  // N*H floats
  float* oacc = h + (size_t)N * H;       // N*H floats
  float* acc  = oacc + (size_t)N * H;    // 1 float

  k_init<<<(N + 255) / 256, 256, 0, stream>>>(deg, acc, N);
  k_deg<<<(E + 255) / 256, 256, 0, stream>>>(dst, eattr, deg, E);
  k_dinv<<<(N + 255) / 256, 256, 0, stream>>>(deg, N);
  k_gemm<<<(N + NB - 1) / NB, 256, 0, stream>>>(x, conv_w, h, N);
  k_outinit<<<(N * H + 255) / 256, 256, 0, stream>>>(h, deg, conv_b, oacc, N);
  k_scatter<<<(E + 3) / 4, 256, 0, stream>>>(src, dst, eattr, deg, h, oacc, E);
  k_reduce<<<1024, 256, 0, stream>>>(oacc, fc_w, acc, N * H);
  k_final<<<1, 64, 0, stream>>>(acc, fc_b, out);
}

// Round 2
// 544.524 us; speedup vs baseline: 1.0316x; 1.0316x over previous
//
#include <hip/hip_runtime.h>
#include <math.h>

constexpr int F = 128;        // in features
constexpr int H = 64;         // out features
constexpr int NB = 32;        // nodes per gemm block
constexpr int XS_STRIDE = F + 4;  // pad to avoid 4-way LDS bank conflict

// ---------------- init: cnt = 0 ---------------------------------------------
__global__ __launch_bounds__(256) void k_init(int* __restrict__ cnt, int N) {
  int i = blockIdx.x * 256 + threadIdx.x;
  if (i < N) cnt[i] = 0;
}

// ---------------- cnt[dst]++ ------------------------------------------------
__global__ __launch_bounds__(256) void k_count(const int* __restrict__ dst,
                                               int* __restrict__ cnt, int E) {
  int e = blockIdx.x * 256 + threadIdx.x;
  if (e < E) atomicAdd(&cnt[dst[e]], 1);
}

// ---------------- exclusive scan cnt -> cursor (single block) ---------------
__global__ __launch_bounds__(1024) void k_scan(const int* __restrict__ cnt,
                                               int* __restrict__ cursor, int N) {
  __shared__ int buf[1024];
  __shared__ int carry;
  const int t = threadIdx.x;
  if (t == 0) carry = 0;
  __syncthreads();
  for (int base = 0; base < N; base += 1024) {
    int i = base + t;
    int v = (i < N) ? cnt[i] : 0;
    buf[t] = v;
    __syncthreads();
    // Hillis-Steele inclusive scan
    for (int off = 1; off < 1024; off <<= 1) {
      int add = (t >= off) ? buf[t - off] : 0;
      __syncthreads();
      buf[t] += add;
      __syncthreads();
    }
    int incl = buf[t];
    int total = buf[1023];
    int c = carry;
    if (i < N) cursor[i] = c + incl - v;   // exclusive
    __syncthreads();
    if (t == 0) carry = c + total;
    __syncthreads();
  }
}

// ---------------- scatter edges into CSR order ------------------------------
__global__ __launch_bounds__(256) void k_fill(const int* __restrict__ src,
                                              const int* __restrict__ dst,
                                              const float* __restrict__ w,
                                              int* __restrict__ cursor,
                                              int2* __restrict__ sorted, int E) {
  int e = blockIdx.x * 256 + threadIdx.x;
  if (e < E) {
    int d = dst[e];
    int pos = atomicAdd(&cursor[d], 1);
    sorted[pos] = make_int2(src[e], __float_as_int(w[e]));
  }
}

// ---------------- deg -> dinv, no atomics (cursor now = segment end) --------
__global__ __launch_bounds__(256) void k_deg2(const int2* __restrict__ sorted,
                                              const int* __restrict__ cursor,
                                              const int* __restrict__ cnt,
                                              float* __restrict__ dinv, int N) {
  int n = blockIdx.x * 256 + threadIdx.x;
  if (n >= N) return;
  int end = cursor[n];
  int start = end - cnt[n];
  float d = 1.0f;                         // self loop
  for (int e = start; e < end; ++e) d += __int_as_float(sorted[e].y);
  dinv[n] = rsqrtf(d);
}

// ---------------- h = x @ W  (N x 128) @ (128 x 64) -------------------------
__global__ __launch_bounds__(256) void k_gemm(const float* __restrict__ x,
                                              const float* __restrict__ W,
                                              float* __restrict__ h, int N) {
  __shared__ float Ws[F * H];            // 32 KB, [k][f]
  __shared__ float xs[NB * XS_STRIDE];   // ~16.5 KB, [nl][k] padded
  const int t = threadIdx.x;
  {
    const float4* W4 = (const float4*)W;
    float4* Ws4 = (float4*)Ws;
#pragma unroll
    for (int i = 0; i < (F * H / 4) / 256; ++i) Ws4[t + i * 256] = W4[t + i * 256];
  }
  const int node0 = blockIdx.x * NB;
  {
    const float4* x4 = (const float4*)(x + (size_t)node0 * F);
    int lim = (N - node0 < NB ? N - node0 : NB) * (F / 4);
    for (int i = t; i < NB * (F / 4); i += 256) {
      int nl = i / (F / 4), kk = i % (F / 4);
      float4 v = (i < lim) ? x4[i] : make_float4(0.f, 0.f, 0.f, 0.f);
      *(float4*)&xs[nl * XS_STRIDE + kk * 4] = v;
    }
  }
  __syncthreads();
  const int f0 = (t & 15) * 4;
  const int nl0 = (t >> 4) * 2;
  float acc[2][4] = {};
  for (int k = 0; k < F; k += 4) {
    float xr[2][4];
    float wr[4][4];
    *(float4*)&xr[0][0] = *(const float4*)&xs[(nl0 + 0) * XS_STRIDE + k];
    *(float4*)&xr[1][0] = *(const float4*)&xs[(nl0 + 1) * XS_STRIDE + k];
#pragma unroll
    for (int i = 0; i < 4; ++i)
      *(float4*)&wr[i][0] = *(const float4*)&Ws[(k + i) * H + f0];
#pragma unroll
    for (int i = 0; i < 4; ++i)
#pragma unroll
      for (int n = 0; n < 2; ++n)
#pragma unroll
        for (int j = 0; j < 4; ++j)
          acc[n][j] += xr[n][i] * wr[i][j];
  }
#pragma unroll
  for (int n = 0; n < 2; ++n) {
    int node = node0 + nl0 + n;
    if (node < N)
      *(float4*)&h[(size_t)node * H + f0] =
          make_float4(acc[n][0], acc[n][1], acc[n][2], acc[n][3]);
  }
}

// ---------------- gather-aggregate + fused relu·dot, wave per node ----------
__global__ __launch_bounds__(256) void k_agg(const int2* __restrict__ sorted,
                                             const int* __restrict__ cursor,
                                             const int* __restrict__ cnt,
                                             const float* __restrict__ dinv,
                                             const float* __restrict__ h,
                                             const float* __restrict__ b,
                                             const float* __restrict__ fcw,
                                             float* __restrict__ partials, int N) {
  const int wid = threadIdx.x >> 6;
  const int lane = threadIdx.x & 63;
  const int n = blockIdx.x * 4 + wid;
  float partial = 0.0f;
  if (n < N) {
    float dn = dinv[n];
    float acc = b[lane] + dn * dn * h[(size_t)n * H + lane];
    int end = cursor[n];
    int e = end - cnt[n];
    for (; e < end; ++e) {
      int2 ew = sorted[e];
      int s = ew.x;
      float nrm = dinv[s] * __int_as_float(ew.y) * dn;
      acc += nrm * h[(size_t)s * H + lane];
    }
    partial = fmaxf(acc, 0.0f) * fcw[(size_t)n * H + lane];
  }
#pragma unroll
  for (int off = 32; off > 0; off >>= 1) partial += __shfl_down(partial, off);
  __shared__ float ls[4];
  if (lane == 0) ls[wid] = partial;
  __syncthreads();
  if (threadIdx.x == 0) partials[blockIdx.x] = ls[0] + ls[1] + ls[2] + ls[3];
}

// ---------------- final: sum partials, + fc_b, sigmoid ----------------------
__global__ __launch_bounds__(1024) void k_fred(const float* __restrict__ partials,
                                               int M,
                                               const float* __restrict__ fcb,
                                               float* __restrict__ out) {
  const int t = threadIdx.x;
  float s = 0.0f;
  for (int i = t; i < M; i += 1024) s += partials[i];
#pragma unroll
  for (int off = 32; off > 0; off >>= 1) s += __shfl_down(s, off);
  __shared__ float ls[16];
  if ((t & 63) == 0) ls[t >> 6] = s;
  __syncthreads();
  if (t == 0) {
    float tot = 0.0f;
#pragma unroll
    for (int i = 0; i < 16; ++i) tot += ls[i];
    float logit = tot + fcb[0];
    out[0] = 1.0f / (1.0f + expf(-logit));
  }
}

extern "C" void kernel_launch(void* const* d_in, const int* in_sizes, int n_in,
                              void* d_out, int out_size, void* d_ws, size_t ws_size,
                              hipStream_t stream) {
  const float* x      = (const float*)d_in[0];
  const int*   elist  = (const int*)d_in[1];
  const float* eattr  = (const float*)d_in[2];
  const float* conv_w = (const float*)d_in[3];
  const float* conv_b = (const float*)d_in[4];
  const float* fc_w   = (const float*)d_in[5];
  const float* fc_b   = (const float*)d_in[6];
  float* out = (float*)d_out;

  const int N = in_sizes[0] / F;   // 50000
  const int E = in_sizes[2];       // 1,600,000
  const int* src = elist;
  const int* dst = elist + E;

  // workspace layout (8-byte aligned pieces first)
  char* wsb = (char*)d_ws;
  int2*  sorted   = (int2*)wsb;                          // E * 8 B
  float* h        = (float*)(wsb + (size_t)E * 8);       // N*H floats
  int*   cnt      = (int*)(h + (size_t)N * H);           // N ints
  int*   cursor   = cnt + N;                             // N ints
  float* dinv     = (float*)(cursor + N);                // N floats
  float* partials = dinv + N;                            // (N+3)/4 floats

  const int nAggBlocks = (N + 3) / 4;

  k_init<<<(N + 255) / 256, 256, 0, stream>>>(cnt, N);
  k_count<<<(E + 255) / 256, 256, 0, stream>>>(dst, cnt, E);
  k_scan<<<1, 1024, 0, stream>>>(cnt, cursor, N);
  k_fill<<<(E + 255) / 256, 256, 0, stream>>>(src, dst, eattr, cursor, sorted, E);
  k_deg2<<<(N + 255) / 256, 256, 0, stream>>>(sorted, cursor, cnt, dinv, N);
  k_gemm<<<(N + NB - 1) / NB, 256, 0, stream>>>(x, conv_w, h, N);
  k_agg<<<nAggBlocks, 256, 0, stream>>>(sorted, cursor, cnt, dinv, h, conv_b, fc_w,
                                        partials, N);
  k_fred<<<1, 1024, 0, stream>>>(partials, nAggBlocks, fc_b, out);
}

// Round 3
// 432.081 us; speedup vs baseline: 1.3000x; 1.2602x over previous
//
#include <hip/hip_runtime.h>
#include <math.h>

constexpr int F = 128;        // in features
constexpr int H = 64;         // out features
constexpr int NB = 32;        // nodes per gemm block
constexpr int XS_STRIDE = F + 4;

// ---------------- init: cnt = 0, deg = 0 ------------------------------------
__global__ __launch_bounds__(256) void k_init(int* __restrict__ cnt,
                                              float* __restrict__ deg, int N) {
  int i = blockIdx.x * 256 + threadIdx.x;
  if (i < N) { cnt[i] = 0; deg[i] = 0.0f; }
}

// ---------------- cnt[dst]++, deg[dst] += w ---------------------------------
__global__ __launch_bounds__(256) void k_count(const int* __restrict__ dst,
                                               const float* __restrict__ w,
                                               int* __restrict__ cnt,
                                               float* __restrict__ deg, int E) {
  int e = blockIdx.x * 256 + threadIdx.x;
  if (e < E) {
    int d = dst[e];
    atomicAdd(&cnt[d], 1);
    atomicAdd(&deg[d], w[e]);
  }
}

// ---------------- dinv = rsqrt(1 + deg) in place ----------------------------
__global__ __launch_bounds__(256) void k_dinv(float* __restrict__ deg, int N) {
  int i = blockIdx.x * 256 + threadIdx.x;
  if (i < N) deg[i] = rsqrtf(1.0f + deg[i]);
}

// ---------------- scan phase 1: per-block exclusive scan + block sum --------
__global__ __launch_bounds__(1024) void k_scan1(const int* __restrict__ cnt,
                                                int* __restrict__ cursor,
                                                int* __restrict__ bsum, int N) {
  __shared__ int buf[1024];
  const int t = threadIdx.x;
  const int i = blockIdx.x * 1024 + t;
  int v = (i < N) ? cnt[i] : 0;
  buf[t] = v;
  __syncthreads();
  for (int off = 1; off < 1024; off <<= 1) {
    int add = (t >= off) ? buf[t - off] : 0;
    __syncthreads();
    buf[t] += add;
    __syncthreads();
  }
  if (i < N) cursor[i] = buf[t] - v;       // exclusive, block-local
  if (t == 1023) bsum[blockIdx.x] = buf[t];
}

// ---------------- scan phase 2: exclusive scan of block sums (tiny) ---------
__global__ void k_scan2(int* __restrict__ bsum, int B) {
  if (threadIdx.x == 0) {
    int run = 0;
    for (int b = 0; b < B; ++b) { int v = bsum[b]; bsum[b] = run; run += v; }
  }
}

// ---------------- scan phase 3: add block offsets ---------------------------
__global__ __launch_bounds__(1024) void k_scan3(int* __restrict__ cursor,
                                                const int* __restrict__ bsum,
                                                int N) {
  int i = blockIdx.x * 1024 + threadIdx.x;
  if (i < N) cursor[i] += bsum[blockIdx.x];
}

// ---------------- fill CSR: sorted[pos] = {src, dinv[src]*w} ----------------
__global__ __launch_bounds__(256) void k_fill(const int* __restrict__ src,
                                              const int* __restrict__ dst,
                                              const float* __restrict__ w,
                                              const float* __restrict__ dinv,
                                              int* __restrict__ cursor,
                                              int2* __restrict__ sorted, int E) {
  int e = blockIdx.x * 256 + threadIdx.x;
  if (e < E) {
    int d = dst[e];
    int s = src[e];
    float sw = dinv[s] * w[e];
    int pos = atomicAdd(&cursor[d], 1);
    sorted[pos] = make_int2(s, __float_as_int(sw));
  }
}

// ---------------- h = x @ W  (N x 128) @ (128 x 64) -------------------------
__global__ __launch_bounds__(256) void k_gemm(const float* __restrict__ x,
                                              const float* __restrict__ W,
                                              float* __restrict__ h, int N) {
  __shared__ float Ws[F * H];
  __shared__ float xs[NB * XS_STRIDE];
  const int t = threadIdx.x;
  {
    const float4* W4 = (const float4*)W;
    float4* Ws4 = (float4*)Ws;
#pragma unroll
    for (int i = 0; i < (F * H / 4) / 256; ++i) Ws4[t + i * 256] = W4[t + i * 256];
  }
  const int node0 = blockIdx.x * NB;
  {
    const float4* x4 = (const float4*)(x + (size_t)node0 * F);
    int lim = (N - node0 < NB ? N - node0 : NB) * (F / 4);
    for (int i = t; i < NB * (F / 4); i += 256) {
      int nl = i / (F / 4), kk = i % (F / 4);
      float4 v = (i < lim) ? x4[i] : make_float4(0.f, 0.f, 0.f, 0.f);
      *(float4*)&xs[nl * XS_STRIDE + kk * 4] = v;
    }
  }
  __syncthreads();
  const int f0 = (t & 15) * 4;
  const int nl0 = (t >> 4) * 2;
  float acc[2][4] = {};
  for (int k = 0; k < F; k += 4) {
    float xr[2][4];
    float wr[4][4];
    *(float4*)&xr[0][0] = *(const float4*)&xs[(nl0 + 0) * XS_STRIDE + k];
    *(float4*)&xr[1][0] = *(const float4*)&xs[(nl0 + 1) * XS_STRIDE + k];
#pragma unroll
    for (int i = 0; i < 4; ++i)
      *(float4*)&wr[i][0] = *(const float4*)&Ws[(k + i) * H + f0];
#pragma unroll
    for (int i = 0; i < 4; ++i)
#pragma unroll
      for (int n = 0; n < 2; ++n)
#pragma unroll
        for (int j = 0; j < 4; ++j)
          acc[n][j] += xr[n][i] * wr[i][j];
  }
#pragma unroll
  for (int n = 0; n < 2; ++n) {
    int node = node0 + nl0 + n;
    if (node < N)
      *(float4*)&h[(size_t)node * H + f0] =
          make_float4(acc[n][0], acc[n][1], acc[n][2], acc[n][3]);
  }
}

// ---- gather-aggregate + fused relu·dot: 16 lanes/node (float4), 4 nodes/wave
__global__ __launch_bounds__(256) void k_agg(const int2* __restrict__ sorted,
                                             const int* __restrict__ cursor,
                                             const int* __restrict__ cnt,
                                             const float* __restrict__ dinv,
                                             const float* __restrict__ h,
                                             const float* __restrict__ b,
                                             const float* __restrict__ fcw,
                                             float* __restrict__ partials, int N) {
  const int wid = threadIdx.x >> 6;
  const int lane = threadIdx.x & 63;
  const int seg = lane >> 4;        // 0..3: node segment within wave
  const int sl = lane & 15;         // lane within segment: 16 x float4 = 64 f
  const int n = blockIdx.x * 16 + wid * 4 + seg;
  const float4* h4 = (const float4*)h;
  float p = 0.0f;
  if (n < N) {
    float dn = dinv[n];
    float4 hn = h4[(size_t)n * 16 + sl];
    float4 bb = ((const float4*)b)[sl];
    float dn2 = dn * dn;
    float ax = bb.x + dn2 * hn.x;
    float ay = bb.y + dn2 * hn.y;
    float az = bb.z + dn2 * hn.z;
    float aw = bb.w + dn2 * hn.w;
    int end = cursor[n];
    int e = end - cnt[n];
    for (; e + 1 < end; e += 2) {
      int2 e0 = sorted[e];
      int2 e1 = sorted[e + 1];
      float4 h0 = h4[(size_t)e0.x * 16 + sl];
      float4 h1 = h4[(size_t)e1.x * 16 + sl];
      float n0 = dn * __int_as_float(e0.y);
      float n1 = dn * __int_as_float(e1.y);
      ax += n0 * h0.x + n1 * h1.x;
      ay += n0 * h0.y + n1 * h1.y;
      az += n0 * h0.z + n1 * h1.z;
      aw += n0 * h0.w + n1 * h1.w;
    }
    if (e < end) {
      int2 e0 = sorted[e];
      float4 h0 = h4[(size_t)e0.x * 16 + sl];
      float n0 = dn * __int_as_float(e0.y);
      ax += n0 * h0.x;
      ay += n0 * h0.y;
      az += n0 * h0.z;
      aw += n0 * h0.w;
    }
    float4 fw = ((const float4*)fcw)[(size_t)n * 16 + sl];
    p = fmaxf(ax, 0.f) * fw.x + fmaxf(ay, 0.f) * fw.y +
        fmaxf(az, 0.f) * fw.z + fmaxf(aw, 0.f) * fw.w;
  }
  // reduce 16 lanes of each segment to sl==0
  p += __shfl_down(p, 8);
  p += __shfl_down(p, 4);
  p += __shfl_down(p, 2);
  p += __shfl_down(p, 1);
  __shared__ float ls[16];
  if (sl == 0) ls[wid * 4 + seg] = p;
  __syncthreads();
  if (threadIdx.x == 0) {
    float s = 0.f;
#pragma unroll
    for (int i = 0; i < 16; ++i) s += ls[i];
    partials[blockIdx.x] = s;
  }
}

// ---------------- final: sum partials, + fc_b, sigmoid ----------------------
__global__ __launch_bounds__(1024) void k_fred(const float* __restrict__ partials,
                                               int M,
                                               const float* __restrict__ fcb,
                                               float* __restrict__ out) {
  const int t = threadIdx.x;
  float s = 0.0f;
  for (int i = t; i < M; i += 1024) s += partials[i];
#pragma unroll
  for (int off = 32; off > 0; off >>= 1) s += __shfl_down(s, off);
  __shared__ float ls[16];
  if ((t & 63) == 0) ls[t >> 6] = s;
  __syncthreads();
  if (t == 0) {
    float tot = 0.0f;
#pragma unroll
    for (int i = 0; i < 16; ++i) tot += ls[i];
    float logit = tot + fcb[0];
    out[0] = 1.0f / (1.0f + expf(-logit));
  }
}

extern "C" void kernel_launch(void* const* d_in, const int* in_sizes, int n_in,
                              void* d_out, int out_size, void* d_ws, size_t ws_size,
                              hipStream_t stream) {
  const float* x      = (const float*)d_in[0];
  const int*   elist  = (const int*)d_in[1];
  const float* eattr  = (const float*)d_in[2];
  const float* conv_w = (const float*)d_in[3];
  const float* conv_b = (const float*)d_in[4];
  const float* fc_w   = (const float*)d_in[5];
  const float* fc_b   = (const float*)d_in[6];
  float* out = (float*)d_out;

  const int N = in_sizes[0] / F;   // 50000
  const int E = in_sizes[2];       // 1,600,000
  const int* src = elist;
  const int* dst = elist + E;

  char* wsb = (char*)d_ws;
  int2*  sorted   = (int2*)wsb;                          // E * 8 B
  float* h        = (float*)(wsb + (size_t)E * 8);       // N*H floats
  int*   cnt      = (int*)(h + (size_t)N * H);           // N ints
  int*   cursor   = cnt + N;                             // N ints
  float* dinv     = (float*)(cursor + N);                // N floats (deg->dinv)
  float* partials = dinv + N;                            // nAgg floats
  const int nAgg = (N + 15) / 16;
  int* bsum = (int*)(partials + nAgg);                   // nScan ints
  const int nScan = (N + 1023) / 1024;

  k_init<<<(N + 255) / 256, 256, 0, stream>>>(cnt, dinv, N);
  k_count<<<(E + 255) / 256, 256, 0, stream>>>(dst, eattr, cnt, dinv, E);
  k_dinv<<<(N + 255) / 256, 256, 0, stream>>>(dinv, N);
  k_scan1<<<nScan, 1024, 0, stream>>>(cnt, cursor, bsum, N);
  k_scan2<<<1, 64, 0, stream>>>(bsum, nScan);
  k_scan3<<<nScan, 1024, 0, stream>>>(cursor, bsum, N);
  k_fill<<<(E + 255) / 256, 256, 0, stream>>>(src, dst, eattr, dinv, cursor, sorted, E);
  k_gemm<<<(N + NB - 1) / NB, 256, 0, stream>>>(x, conv_w, h, N);
  k_agg<<<nAgg, 256, 0, stream>>>(sorted, cursor, cnt, dinv, h, conv_b, fc_w,
                                  partials, N);
  k_fred<<<1, 1024, 0, stream>>>(partials, nAgg, fc_b, out);
}

// Round 4
// 268.048 us; speedup vs baseline: 2.0956x; 1.6120x over previous
//
#include <hip/hip_runtime.h>
#include <hip/hip_bf16.h>
#include <math.h>

constexpr int F = 128;        // in features
constexpr int H = 64;         // out features
constexpr int NB = 32;        // nodes per gemm block
constexpr int XS_STRIDE = F + 4;

#define MASK40 ((1ull << 40) - 1)
#define Q24 16777216.0f

__device__ __forceinline__ float blo(unsigned u) { return __uint_as_float(u << 16); }
__device__ __forceinline__ float bhi(unsigned u) { return __uint_as_float(u & 0xffff0000u); }

// ---------------- init: pk = 0 ----------------------------------------------
__global__ __launch_bounds__(256) void k_init(unsigned long long* __restrict__ pk,
                                              int N) {
  int i = blockIdx.x * 256 + threadIdx.x;
  if (i < N) pk[i] = 0ull;
}

// ------- one packed atomic per edge: cnt in high bits, Q24 deg in low -------
__global__ __launch_bounds__(256) void k_count(const int* __restrict__ dst,
                                               const float* __restrict__ w,
                                               unsigned long long* __restrict__ pk,
                                               int* __restrict__ rank, int E) {
  int e = blockIdx.x * 256 + threadIdx.x;
  if (e < E) {
    int d = dst[e];
    unsigned long long enc =
        (1ull << 40) | (unsigned long long)__float2uint_rn(w[e] * Q24);
    unsigned long long old = atomicAdd(&pk[d], enc);
    rank[e] = (int)(old >> 40);
  }
}

// ---- scan phase 1: unpack cnt/dinv, per-block exclusive scan + block sum ----
__global__ __launch_bounds__(1024) void k_scan1(const unsigned long long* __restrict__ pk,
                                                int* __restrict__ cnt,
                                                float* __restrict__ dinv,
                                                int* __restrict__ cursor,
                                                int* __restrict__ bsum, int N) {
  __shared__ int buf[1024];
  const int t = threadIdx.x;
  const int i = blockIdx.x * 1024 + t;
  int v = 0;
  if (i < N) {
    unsigned long long p = pk[i];
    v = (int)(p >> 40);
    cnt[i] = v;
    dinv[i] = rsqrtf(1.0f + (float)(p & MASK40) * (1.0f / Q24));
  }
  buf[t] = v;
  __syncthreads();
  for (int off = 1; off < 1024; off <<= 1) {
    int add = (t >= off) ? buf[t - off] : 0;
    __syncthreads();
    buf[t] += add;
    __syncthreads();
  }
  if (i < N) cursor[i] = buf[t] - v;       // exclusive, block-local
  if (t == 1023) bsum[blockIdx.x] = buf[t];
}

// ---- scan phase 2+3: add prefix of block sums (<=49 blocks, inline loop) ----
__global__ __launch_bounds__(1024) void k_scan3(int* __restrict__ cursor,
                                                const int* __restrict__ bsum,
                                                int N) {
  __shared__ int off;
  if (threadIdx.x == 0) {
    int s = 0;
    for (int b = 0; b < (int)blockIdx.x; ++b) s += bsum[b];
    off = s;
  }
  __syncthreads();
  int i = blockIdx.x * 1024 + threadIdx.x;
  if (i < N) cursor[i] += off;
}

// ------- fill CSR, atomic-free: sorted[cursor[d]+rank[e]] = {src, dinv*w} ----
__global__ __launch_bounds__(256) void k_fill(const int* __restrict__ src,
                                              const int* __restrict__ dst,
                                              const float* __restrict__ w,
                                              const int* __restrict__ rank,
                                              const float* __restrict__ dinv,
                                              const int* __restrict__ cursor,
                                              int2* __restrict__ sorted, int E) {
  int e = blockIdx.x * 256 + threadIdx.x;
  if (e < E) {
    int d = dst[e];
    int s = src[e];
    float sw = dinv[s] * w[e];
    int pos = cursor[d] + rank[e];
    sorted[pos] = make_int2(s, __float_as_int(sw));
  }
}

// ---------------- h = x @ W, output bf16 (N x 128)@(128 x 64) ---------------
__global__ __launch_bounds__(256) void k_gemm(const float* __restrict__ x,
                                              const float* __restrict__ W,
                                              unsigned short* __restrict__ hb, int N) {
  __shared__ float Ws[F * H];
  __shared__ float xs[NB * XS_STRIDE];
  const int t = threadIdx.x;
  {
    const float4* W4 = (const float4*)W;
    float4* Ws4 = (float4*)Ws;
#pragma unroll
    for (int i = 0; i < (F * H / 4) / 256; ++i) Ws4[t + i * 256] = W4[t + i * 256];
  }
  const int node0 = blockIdx.x * NB;
  {
    const float4* x4 = (const float4*)(x + (size_t)node0 * F);
    int lim = (N - node0 < NB ? N - node0 : NB) * (F / 4);
    for (int i = t; i < NB * (F / 4); i += 256) {
      int nl = i / (F / 4), kk = i % (F / 4);
      float4 v = (i < lim) ? x4[i] : make_float4(0.f, 0.f, 0.f, 0.f);
      *(float4*)&xs[nl * XS_STRIDE + kk * 4] = v;
    }
  }
  __syncthreads();
  const int f0 = (t & 15) * 4;
  const int nl0 = (t >> 4) * 2;
  float acc[2][4] = {};
  for (int k = 0; k < F; k += 4) {
    float xr[2][4];
    float wr[4][4];
    *(float4*)&xr[0][0] = *(const float4*)&xs[(nl0 + 0) * XS_STRIDE + k];
    *(float4*)&xr[1][0] = *(const float4*)&xs[(nl0 + 1) * XS_STRIDE + k];
#pragma unroll
    for (int i = 0; i < 4; ++i)
      *(float4*)&wr[i][0] = *(const float4*)&Ws[(k + i) * H + f0];
#pragma unroll
    for (int i = 0; i < 4; ++i)
#pragma unroll
      for (int n = 0; n < 2; ++n)
#pragma unroll
        for (int j = 0; j < 4; ++j)
          acc[n][j] += xr[n][i] * wr[i][j];
  }
#pragma unroll
  for (int n = 0; n < 2; ++n) {
    int node = node0 + nl0 + n;
    if (node < N) {
      ushort4 o;
      o.x = __bfloat16_as_ushort(__float2bfloat16(acc[n][0]));
      o.y = __bfloat16_as_ushort(__float2bfloat16(acc[n][1]));
      o.z = __bfloat16_as_ushort(__float2bfloat16(acc[n][2]));
      o.w = __bfloat16_as_ushort(__float2bfloat16(acc[n][3]));
      *(ushort4*)&hb[(size_t)node * H + f0] = o;
    }
  }
}

// ---- gather-aggregate (bf16 h) + fused relu·dot: 16 lanes/node, 4 nodes/wave
__global__ __launch_bounds__(256) void k_agg(const int2* __restrict__ sorted,
                                             const int* __restrict__ cursor,
                                             const int* __restrict__ cnt,
                                             const float* __restrict__ dinv,
                                             const unsigned short* __restrict__ hb,
                                             const float* __restrict__ b,
                                             const float* __restrict__ fcw,
                                             float* __restrict__ partials, int N) {
  const int wid = threadIdx.x >> 6;
  const int lane = threadIdx.x & 63;
  const int seg = lane >> 4;        // 0..3: node segment within wave
  const int sl = lane & 15;         // lane within segment: 16 x 4 feats
  const int n = blockIdx.x * 16 + wid * 4 + seg;
  float p = 0.0f;
  if (n < N) {
    float dn = dinv[n];
    uint2 rn = *(const uint2*)(hb + ((size_t)n << 6) + (sl << 2));
    float4 bb = ((const float4*)b)[sl];
    float dn2 = dn * dn;
    float ax = bb.x + dn2 * blo(rn.x);
    float ay = bb.y + dn2 * bhi(rn.x);
    float az = bb.z + dn2 * blo(rn.y);
    float aw = bb.w + dn2 * bhi(rn.y);
    int e = cursor[n];
    int end = e + cnt[n];
    for (; e + 1 < end; e += 2) {
      int2 e0 = sorted[e];
      int2 e1 = sorted[e + 1];
      uint2 r0 = *(const uint2*)(hb + ((size_t)e0.x << 6) + (sl << 2));
      uint2 r1 = *(const uint2*)(hb + ((size_t)e1.x << 6) + (sl << 2));
      float n0 = dn * __int_as_float(e0.y);
      float n1 = dn * __int_as_float(e1.y);
      ax += n0 * blo(r0.x) + n1 * blo(r1.x);
      ay += n0 * bhi(r0.x) + n1 * bhi(r1.x);
      az += n0 * blo(r0.y) + n1 * blo(r1.y);
      aw += n0 * bhi(r0.y) + n1 * bhi(r1.y);
    }
    if (e < end) {
      int2 e0 = sorted[e];
      uint2 r0 = *(const uint2*)(hb + ((size_t)e0.x << 6) + (sl << 2));
      float n0 = dn * __int_as_float(e0.y);
      ax += n0 * blo(r0.x);
      ay += n0 * bhi(r0.x);
      az += n0 * blo(r0.y);
      aw += n0 * bhi(r0.y);
    }
    float4 fw = ((const float4*)fcw)[(size_t)n * 16 + sl];
    p = fmaxf(ax, 0.f) * fw.x + fmaxf(ay, 0.f) * fw.y +
        fmaxf(az, 0.f) * fw.z + fmaxf(aw, 0.f) * fw.w;
  }
  p += __shfl_down(p, 8);
  p += __shfl_down(p, 4);
  p += __shfl_down(p, 2);
  p += __shfl_down(p, 1);
  __shared__ float ls[16];
  if (sl == 0) ls[wid * 4 + seg] = p;
  __syncthreads();
  if (threadIdx.x == 0) {
    float s = 0.f;
#pragma unroll
    for (int i = 0; i < 16; ++i) s += ls[i];
    partials[blockIdx.x] = s;
  }
}

// ---------------- final: sum partials, + fc_b, sigmoid ----------------------
__global__ __launch_bounds__(1024) void k_fred(const float* __restrict__ partials,
                                               int M,
                                               const float* __restrict__ fcb,
                                               float* __restrict__ out) {
  const int t = threadIdx.x;
  float s = 0.0f;
  for (int i = t; i < M; i += 1024) s += partials[i];
#pragma unroll
  for (int off = 32; off > 0; off >>= 1) s += __shfl_down(s, off);
  __shared__ float ls[16];
  if ((t & 63) == 0) ls[t >> 6] = s;
  __syncthreads();
  if (t == 0) {
    float tot = 0.0f;
#pragma unroll
    for (int i = 0; i < 16; ++i) tot += ls[i];
    float logit = tot + fcb[0];
    out[0] = 1.0f / (1.0f + expf(-logit));
  }
}

extern "C" void kernel_launch(void* const* d_in, const int* in_sizes, int n_in,
                              void* d_out, int out_size, void* d_ws, size_t ws_size,
                              hipStream_t stream) {
  const float* x      = (const float*)d_in[0];
  const int*   elist  = (const int*)d_in[1];
  const float* eattr  = (const float*)d_in[2];
  const float* conv_w = (const float*)d_in[3];
  const float* conv_b = (const float*)d_in[4];
  const float* fc_w   = (const float*)d_in[5];
  const float* fc_b   = (const float*)d_in[6];
  float* out = (float*)d_out;

  const int N = in_sizes[0] / F;   // 50000
  const int E = in_sizes[2];       // 1,600,000
  const int* src = elist;
  const int* dst = elist + E;

  char* wsb = (char*)d_ws;
  int2*  sorted = (int2*)wsb;                                   // E*8 B
  unsigned long long* pk = (unsigned long long*)(wsb + (size_t)E * 8);  // N*8 B
  int*   rank   = (int*)(pk + N);                               // E*4 B
  unsigned short* hb = (unsigned short*)(rank + E);             // N*H*2 B
  int*   cnt    = (int*)(hb + (size_t)N * H);                   // N*4
  int*   cursor = cnt + N;                                      // N*4
  float* dinv   = (float*)(cursor + N);                         // N*4
  float* partials = dinv + N;                                   // nAgg*4
  const int nAgg = (N + 15) / 16;
  int* bsum = (int*)(partials + nAgg);                          // nScan*4
  const int nScan = (N + 1023) / 1024;

  k_init<<<(N + 255) / 256, 256, 0, stream>>>(pk, N);
  k_count<<<(E + 255) / 256, 256, 0, stream>>>(dst, eattr, pk, rank, E);
  k_scan1<<<nScan, 1024, 0, stream>>>(pk, cnt, dinv, cursor, bsum, N);
  k_scan3<<<nScan, 1024, 0, stream>>>(cursor, bsum, N);
  k_gemm<<<(N + NB - 1) / NB, 256, 0, stream>>>(x, conv_w, hb, N);
  k_fill<<<(E + 255) / 256, 256, 0, stream>>>(src, dst, eattr, rank, dinv, cursor,
                                              sorted, E);
  k_agg<<<nAgg, 256, 0, stream>>>(sorted, cursor, cnt, dinv, hb, conv_b, fc_w,
                                  partials, N);
  k_fred<<<1, 1024, 0, stream>>>(partials, nAgg, fc_b, out);
}